// Round 1
// baseline (349.457 us; speedup 1.0000x reference)
//
#include <hip/hip_runtime.h>
#include <math.h>

// Problem constants (from reference)
#define BB     8192      // batch
#define DD     512       // embed dim
#define NEXP   16        // expansions per sample
#define TOPK   2048      // round(B * 0.25)
#define NCOL   18        // N_EXP + 2 basis columns
#define AUGX_ROWS (BB + TOPK * NEXP)              // 40960
#define AUGT_OFF  ((size_t)AUGX_ROWS * DD)        // 20971520
#define ISEXP_OFF (AUGT_OFF + AUGX_ROWS)          // 21012480

// ---------------------------------------------------------------------------
// Kernel 1: per-sample score in f64:  x·p / (sqrt(sum x^2+1e-12) sqrt(sum p^2+1e-12))
// one wave (64 threads) per sample
__global__ __launch_bounds__(64) void score_kernel(
    const float* __restrict__ x, const int* __restrict__ y,
    const float* __restrict__ prox, double* __restrict__ scores)
{
    int i = blockIdx.x;
    int lane = threadIdx.x;
    const float* xr = x + (size_t)i * DD;
    const float* pr = prox + (size_t)y[i] * DD;
    double sx = 0.0, sp = 0.0, dp = 0.0;
    #pragma unroll
    for (int e = 0; e < DD; e += 64) {
        float xv = xr[e + lane];
        float pv = pr[e + lane];
        sx += (double)xv * (double)xv;
        sp += (double)pv * (double)pv;
        dp += (double)xv * (double)pv;
    }
    #pragma unroll
    for (int off = 32; off > 0; off >>= 1) {
        sx += __shfl_down(sx, off);
        sp += __shfl_down(sp, off);
        dp += __shfl_down(dp, off);
    }
    if (lane == 0) {
        scores[i] = dp / (sqrt(sx + 1e-12) * sqrt(sp + 1e-12));
    }
}

// ---------------------------------------------------------------------------
// Kernel 2: rank each score; selected iff rank < TOPK.
// Tie-break matches jax.lax.top_k stability: (s_j > s_i) || (s_j==s_i && j<i)
__global__ __launch_bounds__(256) void rank_kernel(
    const double* __restrict__ scores, int* __restrict__ flags)
{
    __shared__ double ch[2048];
    int i = blockIdx.x * 256 + threadIdx.x;
    double si = scores[i];
    int rank = 0;
    for (int base = 0; base < BB; base += 2048) {
        for (int t = threadIdx.x; t < 2048; t += 256) ch[t] = scores[base + t];
        __syncthreads();
        for (int j = 0; j < 2048; ++j) {
            double sj = ch[j];
            int jj = base + j;
            rank += (sj > si || (sj == si && jj < i)) ? 1 : 0;
        }
        __syncthreads();
    }
    flags[i] = (rank < TOPK) ? 1 : 0;
}

// ---------------------------------------------------------------------------
// Kernel 3: ordered compaction (ascending sel[]), write is_expan floats.
// Single block, 256 threads x 32 flags each.
__global__ __launch_bounds__(256) void compact_kernel(
    const int* __restrict__ flags, int* __restrict__ sel, float* __restrict__ out)
{
    __shared__ int wsum[4];
    int t = threadIdx.x;
    int base = t * 32;
    int cnt = 0;
    for (int k = 0; k < 32; ++k) cnt += flags[base + k];
    int lane = t & 63, wave = t >> 6;
    int inc = cnt;
    #pragma unroll
    for (int off = 1; off < 64; off <<= 1) {
        int n = __shfl_up(inc, off);
        if (lane >= off) inc += n;
    }
    if (lane == 63) wsum[wave] = inc;
    __syncthreads();
    int wbase = 0;
    for (int w = 0; w < wave; ++w) wbase += wsum[w];
    int pos = wbase + inc - cnt;   // exclusive prefix over this thread's chunk
    for (int k = 0; k < 32; ++k) {
        int i = base + k;
        int fl = flags[i];
        out[ISEXP_OFF + i] = fl ? 1.0f : 0.0f;
        if (fl) sel[pos++] = i;
    }
}

// ---------------------------------------------------------------------------
// Kernel 4: copy raw x into aug_x[0:B], labels into aug_t[0:B]
__global__ __launch_bounds__(256) void copy_kernel(
    const float* __restrict__ x, const int* __restrict__ y, float* __restrict__ out)
{
    int tid = blockIdx.x * blockDim.x + threadIdx.x;
    const float4* src = (const float4*)x;
    float4* dst = (float4*)out;
    const int nvec = BB * DD / 4;
    for (int idx = tid; idx < nvec; idx += gridDim.x * blockDim.x) dst[idx] = src[idx];
    if (tid < BB) out[AUGT_OFF + tid] = (float)y[tid];
}

// ---------------------------------------------------------------------------
// block sum over 256 threads (4 waves)
__device__ inline float block_sum(float val, volatile float* red, int t)
{
    #pragma unroll
    for (int off = 32; off > 0; off >>= 1) val += __shfl_down(val, off);
    __syncthreads();                 // protect red[] from previous use
    if ((t & 63) == 0) red[t >> 6] = val;
    __syncthreads();
    return red[0] + red[1] + red[2] + red[3];
}

// ---------------------------------------------------------------------------
// Kernel 5: spherical expansion for one selected sample per block (256 thr).
__global__ __launch_bounds__(256) void expand_kernel(
    const float* __restrict__ x, const int* __restrict__ y,
    const float* __restrict__ prox, const float* __restrict__ bw,
    const float* __restrict__ rands, const int* __restrict__ sel,
    float* __restrict__ out)
{
    __shared__ float v[NCOL][DD];    // basis columns (rows here), 36.9 KB
    __shared__ float rbuf[DD];
    __shared__ float coef[NCOL];
    __shared__ float red[4];
    __shared__ float bws[17 * 17];

    int j = blockIdx.x;
    int t = threadIdx.x;
    int wave = t >> 6, lane = t & 63;
    int s = sel[j];
    int cls = y[s];
    const float* xr = x + (size_t)s * DD;
    const float* pr = prox + (size_t)cls * DD;

    for (int k = t; k < 289; k += 256) bws[k] = bw[k];

    // each thread owns elements d0=t and d1=t+256
    float xv0 = xr[t], xv1 = xr[t + 256];
    float pv0 = pr[t], pv1 = pr[t + 256];

    float sx  = block_sum(xv0 * xv0 + xv1 * xv1, red, t);
    float sp  = block_sum(pv0 * pv0 + pv1 * pv1, red, t);
    float dxp = block_sum(xv0 * pv0 + xv1 * pv1, red, t);

    float xn = sqrtf(sx + 1e-12f);
    float pn = sqrtf(sp + 1e-12f);
    float z0 = xv0 / xn, z1 = xv1 / xn;      // normalized sample
    float w0 = pv0 / pn, w1 = pv1 / pn;      // normalized class proxy
    float zw = dxp / (xn * pn);              // dot(z, w_c)

    float M0 = zw * w0, M1 = zw * w1;        // projection onto proxy
    float r10 = z0 - M0, r11 = z1 - M1;
    float r1sq = block_sum(r10 * r10 + r11 * r11, red, t);
    float r1n = sqrtf(r1sq);
    float inv1 = 1.0f / r1n;

    v[0][t] = w0;  v[0][t + 256] = w1;
    v[1][t] = r10 * inv1;  v[1][t + 256] = r11 * inv1;

    // Gram-Schmidt columns 2..17 (classical: coefs from original r)
    for (int i = 2; i < NCOL; ++i) {
        const float* rr = rands + ((size_t)j * NEXP + (i - 2)) * DD;
        float r0 = rr[t], r1v = rr[t + 256];
        rbuf[t] = r0;  rbuf[t + 256] = r1v;
        __syncthreads();   // also covers v[0],v[1] / v[i-1] writes

        // dot products v[c]·r, waves strided over columns
        for (int c = wave; c < i; c += 4) {
            float p = 0.0f;
            #pragma unroll
            for (int e = 0; e < DD; e += 64) p += v[c][e + lane] * rbuf[e + lane];
            #pragma unroll
            for (int off = 32; off > 0; off >>= 1) p += __shfl_down(p, off);
            if (lane == 0) coef[c] = p;
        }
        __syncthreads();

        float nb0 = r0, nb1 = r1v;
        for (int c = 0; c < i; ++c) {
            float cc = coef[c];
            nb0 -= cc * v[c][t];
            nb1 -= cc * v[c][t + 256];
        }
        float nn = block_sum(nb0 * nb0 + nb1 * nb1, red, t);
        float inv = 1.0f / sqrtf(nn);
        v[i][t] = nb0 * inv;  v[i][t + 256] = nb1 * inv;
        __syncthreads();
    }

    // outputs: rows r=1..16 of (M + r1n * bweights @ v[:,1:].T)
    float* orow = out + ((size_t)BB + (size_t)j * NEXP) * DD;
    for (int r = 1; r <= 16; ++r) {
        float acc0 = 0.0f, acc1 = 0.0f;
        #pragma unroll
        for (int c = 0; c < 17; ++c) {
            float b = bws[r * 17 + c];
            acc0 += b * v[1 + c][t];
            acc1 += b * v[1 + c][t + 256];
        }
        orow[(size_t)(r - 1) * DD + t]       = M0 + r1n * acc0;
        orow[(size_t)(r - 1) * DD + t + 256] = M1 + r1n * acc1;
    }

    // expansion labels
    if (t < NEXP) out[AUGT_OFF + BB + (size_t)j * NEXP + t] = (float)cls;
}

// ---------------------------------------------------------------------------
extern "C" void kernel_launch(void* const* d_in, const int* in_sizes, int n_in,
                              void* d_out, int out_size, void* d_ws, size_t ws_size,
                              hipStream_t stream)
{
    const float* x     = (const float*)d_in[0];   // [8192,512]
    const int*   y     = (const int*)d_in[1];     // [8192]
    const float* prox  = (const float*)d_in[2];   // [11318,512]
    const float* bw    = (const float*)d_in[3];   // [17,17]
    const float* rands = (const float*)d_in[4];   // [2048,16,512]
    float* out = (float*)d_out;

    double* scores = (double*)d_ws;                           // 64 KB
    int* flags = (int*)((char*)d_ws + 65536);                 // 32 KB
    int* sel   = (int*)((char*)d_ws + 65536 + 32768);         // 8 KB

    score_kernel<<<BB, 64, 0, stream>>>(x, y, prox, scores);
    rank_kernel<<<BB / 256, 256, 0, stream>>>(scores, flags);
    compact_kernel<<<1, 256, 0, stream>>>(flags, sel, out);
    copy_kernel<<<1024, 256, 0, stream>>>(x, y, out);
    expand_kernel<<<TOPK, 256, 0, stream>>>(x, y, prox, bw, rands, sel, out);
}

// Round 2
// 138.805 us; speedup vs baseline: 2.5176x; 2.5176x over previous
//
#include <hip/hip_runtime.h>
#include <math.h>

// Problem constants (from reference)
#define BB     8192      // batch
#define DD     512       // embed dim
#define NEXP   16        // expansions per sample
#define TOPK   2048      // round(B * 0.25)
#define NCOL   18        // N_EXP + 2 basis columns
#define AUGX_ROWS (BB + TOPK * NEXP)              // 40960
#define AUGT_OFF  ((size_t)AUGX_ROWS * DD)        // 20971520
#define ISEXP_OFF (AUGT_OFF + AUGX_ROWS)          // 21012480

#define JCHUNK 256       // j-scores per rank block

// ---------------------------------------------------------------------------
// Kernel 1: per-sample score in f64:  x·p / (sqrt(sum x^2+1e-12) sqrt(sum p^2+1e-12))
// one wave (64 threads) per sample
__global__ __launch_bounds__(64) void score_kernel(
    const float* __restrict__ x, const int* __restrict__ y,
    const float* __restrict__ prox, double* __restrict__ scores)
{
    int i = blockIdx.x;
    int lane = threadIdx.x;
    const float* xr = x + (size_t)i * DD;
    const float* pr = prox + (size_t)y[i] * DD;
    double sx = 0.0, sp = 0.0, dp = 0.0;
    #pragma unroll
    for (int e = 0; e < DD; e += 64) {
        float xv = xr[e + lane];
        float pv = pr[e + lane];
        sx += (double)xv * (double)xv;
        sp += (double)pv * (double)pv;
        dp += (double)xv * (double)pv;
    }
    #pragma unroll
    for (int off = 32; off > 0; off >>= 1) {
        sx += __shfl_down(sx, off);
        sp += __shfl_down(sp, off);
        dp += __shfl_down(dp, off);
    }
    if (lane == 0) {
        scores[i] = dp / (sqrt(sx + 1e-12) * sqrt(sp + 1e-12));
    }
}

// ---------------------------------------------------------------------------
// Kernel 2: partial rank accumulation. grid = (BB/256, BB/JCHUNK).
// Each block: 256 i's vs one JCHUNK j-slice in LDS; atomicAdd partial ranks.
// Tie-break matches jax.lax.top_k stability: (s_j > s_i) || (s_j==s_i && j<i)
__global__ __launch_bounds__(256) void rank_kernel(
    const double* __restrict__ scores, int* __restrict__ ranks)
{
    __shared__ double ch[JCHUNK];
    int i = blockIdx.x * 256 + threadIdx.x;
    int jbase = blockIdx.y * JCHUNK;
    double si = scores[i];
    if (threadIdx.x < JCHUNK) ch[threadIdx.x] = scores[jbase + threadIdx.x];
    __syncthreads();
    int rank = 0;
    #pragma unroll 8
    for (int j = 0; j < JCHUNK; ++j) {
        double sj = ch[j];
        int jj = jbase + j;
        rank += (sj > si || (sj == si && jj < i)) ? 1 : 0;
    }
    atomicAdd(&ranks[i], rank);
}

// ---------------------------------------------------------------------------
// Kernel 3: ordered compaction (ascending sel[]), write is_expan floats.
// Single block, 256 threads x 32 entries each; reads ranks directly.
__global__ __launch_bounds__(256) void compact_kernel(
    const int* __restrict__ ranks, int* __restrict__ sel, float* __restrict__ out)
{
    __shared__ int wsum[4];
    int t = threadIdx.x;
    int base = t * 32;
    int fl[32];
    int cnt = 0;
    for (int k = 0; k < 32; ++k) {
        fl[k] = (ranks[base + k] < TOPK) ? 1 : 0;
        cnt += fl[k];
    }
    int lane = t & 63, wave = t >> 6;
    int inc = cnt;
    #pragma unroll
    for (int off = 1; off < 64; off <<= 1) {
        int n = __shfl_up(inc, off);
        if (lane >= off) inc += n;
    }
    if (lane == 63) wsum[wave] = inc;
    __syncthreads();
    int wbase = 0;
    for (int w = 0; w < wave; ++w) wbase += wsum[w];
    int pos = wbase + inc - cnt;   // exclusive prefix over this thread's chunk
    for (int k = 0; k < 32; ++k) {
        int i = base + k;
        out[ISEXP_OFF + i] = fl[k] ? 1.0f : 0.0f;
        if (fl[k]) sel[pos++] = i;
    }
}

// ---------------------------------------------------------------------------
// Kernel 4: copy raw x into aug_x[0:B], labels into aug_t[0:B]
__global__ __launch_bounds__(256) void copy_kernel(
    const float* __restrict__ x, const int* __restrict__ y, float* __restrict__ out)
{
    int tid = blockIdx.x * blockDim.x + threadIdx.x;
    const float4* src = (const float4*)x;
    float4* dst = (float4*)out;
    const int nvec = BB * DD / 4;
    for (int idx = tid; idx < nvec; idx += gridDim.x * blockDim.x) dst[idx] = src[idx];
    if (tid < BB) out[AUGT_OFF + tid] = (float)y[tid];
}

// ---------------------------------------------------------------------------
// block sum over 256 threads (4 waves)
__device__ inline float block_sum(float val, volatile float* red, int t)
{
    #pragma unroll
    for (int off = 32; off > 0; off >>= 1) val += __shfl_down(val, off);
    __syncthreads();                 // protect red[] from previous use
    if ((t & 63) == 0) red[t >> 6] = val;
    __syncthreads();
    return red[0] + red[1] + red[2] + red[3];
}

// ---------------------------------------------------------------------------
// Kernel 5: spherical expansion for one selected sample per block (256 thr).
__global__ __launch_bounds__(256) void expand_kernel(
    const float* __restrict__ x, const int* __restrict__ y,
    const float* __restrict__ prox, const float* __restrict__ bw,
    const float* __restrict__ rands, const int* __restrict__ sel,
    float* __restrict__ out)
{
    __shared__ float v[NCOL][DD];    // basis columns (rows here), 36.9 KB
    __shared__ float rbuf[DD];
    __shared__ float coef[NCOL];
    __shared__ float red[4];
    __shared__ float bws[17 * 17];

    int j = blockIdx.x;
    int t = threadIdx.x;
    int wave = t >> 6, lane = t & 63;
    int s = sel[j];
    int cls = y[s];
    const float* xr = x + (size_t)s * DD;
    const float* pr = prox + (size_t)cls * DD;

    for (int k = t; k < 289; k += 256) bws[k] = bw[k];

    // each thread owns elements d0=t and d1=t+256
    float xv0 = xr[t], xv1 = xr[t + 256];
    float pv0 = pr[t], pv1 = pr[t + 256];

    float sx  = block_sum(xv0 * xv0 + xv1 * xv1, red, t);
    float sp  = block_sum(pv0 * pv0 + pv1 * pv1, red, t);
    float dxp = block_sum(xv0 * pv0 + xv1 * pv1, red, t);

    float xn = sqrtf(sx + 1e-12f);
    float pn = sqrtf(sp + 1e-12f);
    float z0 = xv0 / xn, z1 = xv1 / xn;      // normalized sample
    float w0 = pv0 / pn, w1 = pv1 / pn;      // normalized class proxy
    float zw = dxp / (xn * pn);              // dot(z, w_c)

    float M0 = zw * w0, M1 = zw * w1;        // projection onto proxy
    float r10 = z0 - M0, r11 = z1 - M1;
    float r1sq = block_sum(r10 * r10 + r11 * r11, red, t);
    float r1n = sqrtf(r1sq);
    float inv1 = 1.0f / r1n;

    v[0][t] = w0;  v[0][t + 256] = w1;
    v[1][t] = r10 * inv1;  v[1][t + 256] = r11 * inv1;

    // Gram-Schmidt columns 2..17 (classical: coefs from original r)
    for (int i = 2; i < NCOL; ++i) {
        const float* rr = rands + ((size_t)j * NEXP + (i - 2)) * DD;
        float r0 = rr[t], r1v = rr[t + 256];
        rbuf[t] = r0;  rbuf[t + 256] = r1v;
        __syncthreads();   // also covers v[0],v[1] / v[i-1] writes

        // dot products v[c]·r, waves strided over columns
        for (int c = wave; c < i; c += 4) {
            float p = 0.0f;
            #pragma unroll
            for (int e = 0; e < DD; e += 64) p += v[c][e + lane] * rbuf[e + lane];
            #pragma unroll
            for (int off = 32; off > 0; off >>= 1) p += __shfl_down(p, off);
            if (lane == 0) coef[c] = p;
        }
        __syncthreads();

        float nb0 = r0, nb1 = r1v;
        for (int c = 0; c < i; ++c) {
            float cc = coef[c];
            nb0 -= cc * v[c][t];
            nb1 -= cc * v[c][t + 256];
        }
        float nn = block_sum(nb0 * nb0 + nb1 * nb1, red, t);
        float inv = 1.0f / sqrtf(nn);
        v[i][t] = nb0 * inv;  v[i][t + 256] = nb1 * inv;
        __syncthreads();
    }

    // outputs: rows r=1..16 of (M + r1n * bweights @ v[:,1:].T)
    float* orow = out + ((size_t)BB + (size_t)j * NEXP) * DD;
    for (int r = 1; r <= 16; ++r) {
        float acc0 = 0.0f, acc1 = 0.0f;
        #pragma unroll
        for (int c = 0; c < 17; ++c) {
            float b = bws[r * 17 + c];
            acc0 += b * v[1 + c][t];
            acc1 += b * v[1 + c][t + 256];
        }
        orow[(size_t)(r - 1) * DD + t]       = M0 + r1n * acc0;
        orow[(size_t)(r - 1) * DD + t + 256] = M1 + r1n * acc1;
    }

    // expansion labels
    if (t < NEXP) out[AUGT_OFF + BB + (size_t)j * NEXP + t] = (float)cls;
}

// ---------------------------------------------------------------------------
extern "C" void kernel_launch(void* const* d_in, const int* in_sizes, int n_in,
                              void* d_out, int out_size, void* d_ws, size_t ws_size,
                              hipStream_t stream)
{
    const float* x     = (const float*)d_in[0];   // [8192,512]
    const int*   y     = (const int*)d_in[1];     // [8192]
    const float* prox  = (const float*)d_in[2];   // [11318,512]
    const float* bw    = (const float*)d_in[3];   // [17,17]
    const float* rands = (const float*)d_in[4];   // [2048,16,512]
    float* out = (float*)d_out;

    double* scores = (double*)d_ws;                           // 64 KB
    int* ranks = (int*)((char*)d_ws + 65536);                 // 32 KB
    int* sel   = (int*)((char*)d_ws + 65536 + 32768);         // 8 KB

    hipMemsetAsync(ranks, 0, BB * sizeof(int), stream);

    score_kernel<<<BB, 64, 0, stream>>>(x, y, prox, scores);
    dim3 rgrid(BB / 256, BB / JCHUNK);
    rank_kernel<<<rgrid, 256, 0, stream>>>(scores, ranks);
    compact_kernel<<<1, 256, 0, stream>>>(ranks, sel, out);
    copy_kernel<<<1024, 256, 0, stream>>>(x, y, out);
    expand_kernel<<<TOPK, 256, 0, stream>>>(x, y, prox, bw, rands, sel, out);
}

// Round 3
// 134.675 us; speedup vs baseline: 2.5948x; 1.0307x over previous
//
#include <hip/hip_runtime.h>
#include <math.h>

// Problem constants (from reference)
#define BB     8192      // batch
#define DD     512       // embed dim
#define NEXP   16        // expansions per sample
#define TOPK   2048      // round(B * 0.25)
#define AUGX_ROWS (BB + TOPK * NEXP)              // 40960
#define AUGT_OFF  ((size_t)AUGX_ROWS * DD)        // 20971520
#define ISEXP_OFF (AUGT_OFF + AUGX_ROWS)          // 21012480

#define JCHUNK 256       // j-scores per rank block

// ---------------------------------------------------------------------------
// Kernel 1: per-sample score in f64 (matches harness ordering at ties)
__global__ __launch_bounds__(64) void score_kernel(
    const float* __restrict__ x, const int* __restrict__ y,
    const float* __restrict__ prox, double* __restrict__ scores)
{
    int i = blockIdx.x;
    int lane = threadIdx.x;
    const float* xr = x + (size_t)i * DD;
    const float* pr = prox + (size_t)y[i] * DD;
    double sx = 0.0, sp = 0.0, dp = 0.0;
    #pragma unroll
    for (int e = 0; e < DD; e += 64) {
        float xv = xr[e + lane];
        float pv = pr[e + lane];
        sx += (double)xv * (double)xv;
        sp += (double)pv * (double)pv;
        dp += (double)xv * (double)pv;
    }
    #pragma unroll
    for (int off = 32; off > 0; off >>= 1) {
        sx += __shfl_down(sx, off);
        sp += __shfl_down(sp, off);
        dp += __shfl_down(dp, off);
    }
    if (lane == 0) {
        scores[i] = dp / (sqrt(sx + 1e-12) * sqrt(sp + 1e-12));
    }
}

// ---------------------------------------------------------------------------
// Kernel 2: partial rank accumulation; tie-break = jax.lax.top_k stability.
__global__ __launch_bounds__(256) void rank_kernel(
    const double* __restrict__ scores, int* __restrict__ ranks)
{
    __shared__ double ch[JCHUNK];
    int i = blockIdx.x * 256 + threadIdx.x;
    int jbase = blockIdx.y * JCHUNK;
    double si = scores[i];
    if (threadIdx.x < JCHUNK) ch[threadIdx.x] = scores[jbase + threadIdx.x];
    __syncthreads();
    int rank = 0;
    #pragma unroll 8
    for (int j = 0; j < JCHUNK; ++j) {
        double sj = ch[j];
        int jj = jbase + j;
        rank += (sj > si || (sj == si && jj < i)) ? 1 : 0;
    }
    atomicAdd(&ranks[i], rank);
}

// ---------------------------------------------------------------------------
// Kernel 3: ordered compaction (ascending sel[]), write is_expan floats.
__global__ __launch_bounds__(256) void compact_kernel(
    const int* __restrict__ ranks, int* __restrict__ sel, float* __restrict__ out)
{
    __shared__ int wsum[4];
    int t = threadIdx.x;
    int base = t * 32;
    int fl[32];
    int cnt = 0;
    for (int k = 0; k < 32; ++k) {
        fl[k] = (ranks[base + k] < TOPK) ? 1 : 0;
        cnt += fl[k];
    }
    int lane = t & 63, wave = t >> 6;
    int inc = cnt;
    #pragma unroll
    for (int off = 1; off < 64; off <<= 1) {
        int n = __shfl_up(inc, off);
        if (lane >= off) inc += n;
    }
    if (lane == 63) wsum[wave] = inc;
    __syncthreads();
    int wbase = 0;
    for (int w = 0; w < wave; ++w) wbase += wsum[w];
    int pos = wbase + inc - cnt;
    for (int k = 0; k < 32; ++k) {
        int i = base + k;
        out[ISEXP_OFF + i] = fl[k] ? 1.0f : 0.0f;
        if (fl[k]) sel[pos++] = i;
    }
}

// ---------------------------------------------------------------------------
// Kernel 4: copy raw x into aug_x[0:B], labels into aug_t[0:B]
__global__ __launch_bounds__(256) void copy_kernel(
    const float* __restrict__ x, const int* __restrict__ y, float* __restrict__ out)
{
    int tid = blockIdx.x * blockDim.x + threadIdx.x;
    const float4* src = (const float4*)x;
    float4* dst = (float4*)out;
    const int nvec = BB * DD / 4;
    for (int idx = tid; idx < nvec; idx += gridDim.x * blockDim.x) dst[idx] = src[idx];
    if (tid < BB) out[AUGT_OFF + tid] = (float)y[tid];
}

// ---------------------------------------------------------------------------
__device__ inline void block_sum3(float& a, float& b, float& c, float* red, int t)
{
    #pragma unroll
    for (int off = 32; off > 0; off >>= 1) {
        a += __shfl_down(a, off);
        b += __shfl_down(b, off);
        c += __shfl_down(c, off);
    }
    __syncthreads();
    if ((t & 63) == 0) { int w = t >> 6; red[w] = a; red[4 + w] = b; red[8 + w] = c; }
    __syncthreads();
    a = red[0] + red[1] + red[2] + red[3];
    b = red[4] + red[5] + red[6] + red[7];
    c = red[8] + red[9] + red[10] + red[11];
}

__device__ inline float block_sum1(float v, float* red, int t)
{
    #pragma unroll
    for (int off = 32; off > 0; off >>= 1) v += __shfl_down(v, off);
    __syncthreads();
    if ((t & 63) == 0) red[t >> 6] = v;
    __syncthreads();
    return red[0] + red[1] + red[2] + red[3];
}

// ---------------------------------------------------------------------------
// Kernel 5: spherical expansion via coefficient-space Gram-Schmidt.
// One sample per 256-thread block; thread t owns dims {2t, 2t+1}.
__global__ __launch_bounds__(256, 4) void expand_kernel(
    const float* __restrict__ x, const int* __restrict__ y,
    const float* __restrict__ prox, const float* __restrict__ bwg,
    const float* __restrict__ rands, const int* __restrict__ sel,
    float* __restrict__ out)
{
    __shared__ float Bm[18][DD];     // 36864 B: rows w, u1, r0..r15
    __shared__ float G[18][18];      // Gram matrix; reused as C after GS
    __shared__ float As[18][18];     // GS coefficient matrix (rows 1..17 used)
    __shared__ float red[12];

    const int j = blockIdx.x;
    const int t = threadIdx.x;
    const int wave = t >> 6, lane = t & 63;
    const int s = sel[j];
    const int cls = y[s];

    float2 xv = ((const float2*)(x + (size_t)s * DD))[t];
    float2 pv = ((const float2*)(prox + (size_t)cls * DD))[t];
    float2 rv[NEXP];
    #pragma unroll
    for (int k = 0; k < NEXP; ++k)
        rv[k] = ((const float2*)(rands + ((size_t)j * NEXP + k) * DD))[t];

    float sx  = xv.x * xv.x + xv.y * xv.y;
    float sp  = pv.x * pv.x + pv.y * pv.y;
    float dxp = xv.x * pv.x + xv.y * pv.y;
    block_sum3(sx, sp, dxp, red, t);

    float xn = sqrtf(sx + 1e-12f), pn = sqrtf(sp + 1e-12f);
    float2 z  = { xv.x / xn, xv.y / xn };
    float2 w  = { pv.x / pn, pv.y / pn };
    float zw  = dxp / (xn * pn);
    float2 M  = { zw * w.x, zw * w.y };
    float2 r1 = { z.x - M.x, z.y - M.y };
    float r1sq = block_sum1(r1.x * r1.x + r1.y * r1.y, red, t);
    float r1n = sqrtf(r1sq);
    float inv1 = 1.0f / r1n;
    float2 u1 = { r1.x * inv1, r1.y * inv1 };

    ((float2*)Bm[0])[t] = w;
    ((float2*)Bm[1])[t] = u1;
    #pragma unroll
    for (int k = 0; k < NEXP; ++k) ((float2*)Bm[2 + k])[t] = rv[k];
    __syncthreads();

    // --- Gram matrix: 171 independent 512-dots, wave-per-a-row with reuse
    for (int a = wave; a < 18; a += 4) {
        float4 a0 = *(const float4*)&Bm[a][lane * 8];
        float4 a1 = *(const float4*)&Bm[a][lane * 8 + 4];
        for (int b = a; b < 18; ++b) {
            float4 b0 = *(const float4*)&Bm[b][lane * 8];
            float4 b1 = *(const float4*)&Bm[b][lane * 8 + 4];
            float p = a0.x * b0.x + a0.y * b0.y + a0.z * b0.z + a0.w * b0.w
                    + a1.x * b1.x + a1.y * b1.y + a1.z * b1.z + a1.w * b1.w;
            #pragma unroll
            for (int off = 32; off > 0; off >>= 1) p += __shfl_xor(p, off);
            if (lane == 0) { G[a][b] = p; G[b][a] = p; }
        }
    }
    __syncthreads();

    // --- coefficient-space classical GS (wave 0; lane = basis column j)
    if (wave == 0) {
        const bool act = (lane < 18);
        const int gl = act ? lane : 0;     // clamped LDS row
        float Ac[18];                      // Ac[c] = A[c][lane], static-indexed
        #pragma unroll
        for (int c = 0; c < 18; ++c) Ac[c] = 0.0f;
        if (lane == 0) Ac[0] = 1.0f;
        if (lane == 1) Ac[1] = 1.0f;
        #pragma unroll
        for (int i = 2; i < 18; ++i) {
            float gji = act ? G[gl][i] : 0.0f;
            float na = (lane == i) ? 1.0f : 0.0f;
            #pragma unroll
            for (int c = 0; c < i; ++c) {
                // coef_c = sum_j A[c][j] * G[j][i]  (butterfly over 32 lanes)
                float p = Ac[c] * gji;
                p += __shfl_xor(p, 16); p += __shfl_xor(p, 8);
                p += __shfl_xor(p, 4);  p += __shfl_xor(p, 2);
                p += __shfl_xor(p, 1);
                na -= p * Ac[c];
            }
            // norm^2 = na^T G na (na supported on lanes 0..i)
            float ssum = 0.0f;
            #pragma unroll
            for (int k = 0; k <= i; ++k) {
                float nak = __shfl(na, k);
                float gjk = act ? G[gl][k] : 0.0f;
                ssum += gjk * nak;
            }
            ssum *= na;
            #pragma unroll
            for (int off = 16; off > 0; off >>= 1) ssum += __shfl_xor(ssum, off);
            float inv = 1.0f / sqrtf(ssum);
            Ac[i] = na * inv;
        }
        if (act) {
            #pragma unroll
            for (int c = 1; c < 18; ++c) As[c][lane] = Ac[c];
        }
    }
    __syncthreads();

    // --- C = bweights rows 1..16 @ A[1:18]  (stored into G's space)
    for (int e = t; e < 16 * 18; e += 256) {
        int r = e / 18, jj = e - r * 18;
        float acc = 0.0f;
        #pragma unroll
        for (int c = 0; c < 17; ++c)
            acc += bwg[(r + 1) * 17 + c] * As[1 + c][jj];
        G[r][jj] = acc;
    }
    __syncthreads();

    // --- outputs: out_r = M + r1n * sum_j C[r][j] * b_j  (b_j from registers)
    float Br0[18], Br1[18];
    Br0[0] = w.x;  Br1[0] = w.y;
    Br0[1] = u1.x; Br1[1] = u1.y;
    #pragma unroll
    for (int k = 0; k < NEXP; ++k) { Br0[2 + k] = rv[k].x; Br1[2 + k] = rv[k].y; }

    float* orow = out + ((size_t)BB + (size_t)j * NEXP) * DD;
    #pragma unroll
    for (int r = 0; r < 16; ++r) {
        float o0 = 0.0f, o1 = 0.0f;
        #pragma unroll
        for (int jj = 0; jj < 18; ++jj) {
            float cc = G[r][jj];
            o0 += cc * Br0[jj];
            o1 += cc * Br1[jj];
        }
        float2 ov = { M.x + r1n * o0, M.y + r1n * o1 };
        ((float2*)(orow + (size_t)r * DD))[t] = ov;
    }

    if (t < NEXP) out[AUGT_OFF + BB + (size_t)j * NEXP + t] = (float)cls;
}

// ---------------------------------------------------------------------------
extern "C" void kernel_launch(void* const* d_in, const int* in_sizes, int n_in,
                              void* d_out, int out_size, void* d_ws, size_t ws_size,
                              hipStream_t stream)
{
    const float* x     = (const float*)d_in[0];   // [8192,512]
    const int*   y     = (const int*)d_in[1];     // [8192]
    const float* prox  = (const float*)d_in[2];   // [11318,512]
    const float* bw    = (const float*)d_in[3];   // [17,17]
    const float* rands = (const float*)d_in[4];   // [2048,16,512]
    float* out = (float*)d_out;

    double* scores = (double*)d_ws;                           // 64 KB
    int* ranks = (int*)((char*)d_ws + 65536);                 // 32 KB
    int* sel   = (int*)((char*)d_ws + 65536 + 32768);         // 8 KB

    hipMemsetAsync(ranks, 0, BB * sizeof(int), stream);

    score_kernel<<<BB, 64, 0, stream>>>(x, y, prox, scores);
    dim3 rgrid(BB / 256, BB / JCHUNK);
    rank_kernel<<<rgrid, 256, 0, stream>>>(scores, ranks);
    compact_kernel<<<1, 256, 0, stream>>>(ranks, sel, out);
    copy_kernel<<<1024, 256, 0, stream>>>(x, y, out);
    expand_kernel<<<TOPK, 256, 0, stream>>>(x, y, prox, bw, rands, sel, out);
}

// Round 4
// 109.712 us; speedup vs baseline: 3.1852x; 1.2275x over previous
//
#include <hip/hip_runtime.h>
#include <math.h>

// Problem constants (from reference)
#define BB     8192      // batch
#define DD     512       // embed dim
#define NEXP   16        // expansions per sample
#define TOPK   2048      // round(B * 0.25)
#define AUGX_ROWS (BB + TOPK * NEXP)              // 40960
#define AUGT_OFF  ((size_t)AUGX_ROWS * DD)        // 20971520
#define ISEXP_OFF (AUGT_OFF + AUGX_ROWS)          // 21012480

#define JCHUNK 256       // j-scores per rank block

// ---------------------------------------------------------------------------
// Kernel 1: per-sample score in f64 (matches harness ordering at ties)
__global__ __launch_bounds__(64) void score_kernel(
    const float* __restrict__ x, const int* __restrict__ y,
    const float* __restrict__ prox, double* __restrict__ scores)
{
    int i = blockIdx.x;
    int lane = threadIdx.x;
    const float* xr = x + (size_t)i * DD;
    const float* pr = prox + (size_t)y[i] * DD;
    double sx = 0.0, sp = 0.0, dp = 0.0;
    #pragma unroll
    for (int e = 0; e < DD; e += 64) {
        float xv = xr[e + lane];
        float pv = pr[e + lane];
        sx += (double)xv * (double)xv;
        sp += (double)pv * (double)pv;
        dp += (double)xv * (double)pv;
    }
    #pragma unroll
    for (int off = 32; off > 0; off >>= 1) {
        sx += __shfl_down(sx, off);
        sp += __shfl_down(sp, off);
        dp += __shfl_down(dp, off);
    }
    if (lane == 0) {
        scores[i] = dp / (sqrt(sx + 1e-12) * sqrt(sp + 1e-12));
    }
}

// ---------------------------------------------------------------------------
// Kernel 2: partial rank accumulation; tie-break = jax.lax.top_k stability.
__global__ __launch_bounds__(256) void rank_kernel(
    const double* __restrict__ scores, int* __restrict__ ranks)
{
    __shared__ double ch[JCHUNK];
    int i = blockIdx.x * 256 + threadIdx.x;
    int jbase = blockIdx.y * JCHUNK;
    double si = scores[i];
    if (threadIdx.x < JCHUNK) ch[threadIdx.x] = scores[jbase + threadIdx.x];
    __syncthreads();
    int rank = 0;
    #pragma unroll 8
    for (int j = 0; j < JCHUNK; ++j) {
        double sj = ch[j];
        int jj = jbase + j;
        rank += (sj > si || (sj == si && jj < i)) ? 1 : 0;
    }
    atomicAdd(&ranks[i], rank);
}

// ---------------------------------------------------------------------------
// Kernel 3: ordered compaction (ascending sel[]), write is_expan floats.
__global__ __launch_bounds__(256) void compact_kernel(
    const int* __restrict__ ranks, int* __restrict__ sel, float* __restrict__ out)
{
    __shared__ int wsum[4];
    int t = threadIdx.x;
    int base = t * 32;
    int fl[32];
    int cnt = 0;
    for (int k = 0; k < 32; ++k) {
        fl[k] = (ranks[base + k] < TOPK) ? 1 : 0;
        cnt += fl[k];
    }
    int lane = t & 63, wave = t >> 6;
    int inc = cnt;
    #pragma unroll
    for (int off = 1; off < 64; off <<= 1) {
        int n = __shfl_up(inc, off);
        if (lane >= off) inc += n;
    }
    if (lane == 63) wsum[wave] = inc;
    __syncthreads();
    int wbase = 0;
    for (int w = 0; w < wave; ++w) wbase += wsum[w];
    int pos = wbase + inc - cnt;
    for (int k = 0; k < 32; ++k) {
        int i = base + k;
        out[ISEXP_OFF + i] = fl[k] ? 1.0f : 0.0f;
        if (fl[k]) sel[pos++] = i;
    }
}

// ---------------------------------------------------------------------------
// Kernel 4: copy raw x into aug_x[0:B], labels into aug_t[0:B]
__global__ __launch_bounds__(256) void copy_kernel(
    const float* __restrict__ x, const int* __restrict__ y, float* __restrict__ out)
{
    int tid = blockIdx.x * blockDim.x + threadIdx.x;
    const float4* src = (const float4*)x;
    float4* dst = (float4*)out;
    const int nvec = BB * DD / 4;
    for (int idx = tid; idx < nvec; idx += gridDim.x * blockDim.x) dst[idx] = src[idx];
    if (tid < BB) out[AUGT_OFF + tid] = (float)y[tid];
}

// ---------------------------------------------------------------------------
__device__ inline void block_sum3(float& a, float& b, float& c, float* red, int t)
{
    #pragma unroll
    for (int off = 32; off > 0; off >>= 1) {
        a += __shfl_down(a, off);
        b += __shfl_down(b, off);
        c += __shfl_down(c, off);
    }
    __syncthreads();
    if ((t & 63) == 0) { int w = t >> 6; red[w] = a; red[4 + w] = b; red[8 + w] = c; }
    __syncthreads();
    a = red[0] + red[1] + red[2] + red[3];
    b = red[4] + red[5] + red[6] + red[7];
    c = red[8] + red[9] + red[10] + red[11];
}

__device__ inline float block_sum1(float v, float* red, int t)
{
    #pragma unroll
    for (int off = 32; off > 0; off >>= 1) v += __shfl_down(v, off);
    __syncthreads();
    if ((t & 63) == 0) red[t >> 6] = v;
    __syncthreads();
    return red[0] + red[1] + red[2] + red[3];
}

// ---------------------------------------------------------------------------
// Kernel 5: spherical expansion. Coefficient-space orthogonalization via
// Cholesky of the 18x18 Gram (A = L^-1), outputs via C = bw_ext @ L^-1
// (16 independent back-substitutions). One sample per 256-thread block;
// thread t owns dims {2t, 2t+1}.
__global__ __launch_bounds__(256, 4) void expand_kernel(
    const float* __restrict__ x, const int* __restrict__ y,
    const float* __restrict__ prox, const float* __restrict__ bwg,
    const float* __restrict__ rands, const int* __restrict__ sel,
    float* __restrict__ out)
{
    __shared__ float Bm[18][DD];     // 36864 B: rows w, u1, r0..r15
    __shared__ float G[18][18];      // Gram matrix; rows 0..15 reused as C
    __shared__ float Ls[18][18];     // Cholesky factor (lower)
    __shared__ float invd[18];       // 1 / L[k][k]
    __shared__ float bws[16 * 17];   // bweights rows 1..16
    __shared__ float red[12];

    const int j = blockIdx.x;
    const int t = threadIdx.x;
    const int wave = t >> 6, lane = t & 63;
    const int s = sel[j];
    const int cls = y[s];

    // stage bweights rows 1..16 (linear: bwg[17 .. 17+272))
    for (int k = t; k < 16 * 17; k += 256) bws[k] = bwg[17 + k];

    float2 xv = ((const float2*)(x + (size_t)s * DD))[t];
    float2 pv = ((const float2*)(prox + (size_t)cls * DD))[t];
    float2 rv[NEXP];
    #pragma unroll
    for (int k = 0; k < NEXP; ++k)
        rv[k] = ((const float2*)(rands + ((size_t)j * NEXP + k) * DD))[t];

    float sx  = xv.x * xv.x + xv.y * xv.y;
    float sp  = pv.x * pv.x + pv.y * pv.y;
    float dxp = xv.x * pv.x + xv.y * pv.y;
    block_sum3(sx, sp, dxp, red, t);

    float xn = sqrtf(sx + 1e-12f), pn = sqrtf(sp + 1e-12f);
    float2 z  = { xv.x / xn, xv.y / xn };
    float2 w  = { pv.x / pn, pv.y / pn };
    float zw  = dxp / (xn * pn);
    float2 M  = { zw * w.x, zw * w.y };
    float2 r1 = { z.x - M.x, z.y - M.y };
    float r1sq = block_sum1(r1.x * r1.x + r1.y * r1.y, red, t);
    float r1n = sqrtf(r1sq);
    float inv1 = 1.0f / r1n;
    float2 u1 = { r1.x * inv1, r1.y * inv1 };

    ((float2*)Bm[0])[t] = w;
    ((float2*)Bm[1])[t] = u1;
    #pragma unroll
    for (int k = 0; k < NEXP; ++k) ((float2*)Bm[2 + k])[t] = rv[k];
    __syncthreads();

    // --- Gram matrix: 171 independent 512-dots, wave-per-a-row with reuse
    for (int a = wave; a < 18; a += 4) {
        float4 a0 = *(const float4*)&Bm[a][lane * 8];
        float4 a1 = *(const float4*)&Bm[a][lane * 8 + 4];
        for (int b = a; b < 18; ++b) {
            float4 b0 = *(const float4*)&Bm[b][lane * 8];
            float4 b1 = *(const float4*)&Bm[b][lane * 8 + 4];
            float p = a0.x * b0.x + a0.y * b0.y + a0.z * b0.z + a0.w * b0.w
                    + a1.x * b1.x + a1.y * b1.y + a1.z * b1.z + a1.w * b1.w;
            #pragma unroll
            for (int off = 32; off > 0; off >>= 1) p += __shfl_xor(p, off);
            if (lane == 0) { G[a][b] = p; G[b][a] = p; }
        }
    }
    __syncthreads();

    // --- wave 0: Cholesky G = L L^T (lane = row), then 16 back-solves.
    if (wave == 0) {
        const int jl = (lane < 18) ? lane : 17;   // rows; lanes >=18 duplicate 17
        float Lrow[18];                           // this lane's row of L
        #pragma unroll
        for (int col = 0; col < 18; ++col) {
            float sv = G[jl][col];
            #pragma unroll
            for (int m = 0; m < col; ++m)
                sv -= Lrow[m] * Ls[col][m];       // Ls[col][m]: broadcast read
            float scol = __shfl(sv, col);         // diag pivot (readlane)
            float rsq = rsqrtf(scol);
            float lv = (jl >= col) ? sv * rsq : 0.0f;
            Lrow[col] = lv;
            if (lane < 18) Ls[jl][col] = lv;
            if (lane == 0) invd[col] = rsq;       // 1/L[col][col]
        }
        // back-substitution: lane r solves L^T c = bw_ext_r  (r = 0..15)
        if (lane < 16) {
            float xreg[18];
            #pragma unroll
            for (int k = 17; k >= 0; --k) {
                float sv = (k == 0) ? 0.0f : bws[lane * 17 + (k - 1)];
                #pragma unroll
                for (int m = k + 1; m < 18; ++m)
                    sv -= Ls[m][k] * xreg[m];     // broadcast reads
                xreg[k] = sv * invd[k];
            }
            #pragma unroll
            for (int k = 0; k < 18; ++k) G[lane][k] = xreg[k];  // C rows 0..15
        }
    }
    __syncthreads();

    // --- outputs: out_r = M + r1n * sum_j C[r][j] * b_j  (b_j from registers)
    float Br0[18], Br1[18];
    Br0[0] = w.x;  Br1[0] = w.y;
    Br0[1] = u1.x; Br1[1] = u1.y;
    #pragma unroll
    for (int k = 0; k < NEXP; ++k) { Br0[2 + k] = rv[k].x; Br1[2 + k] = rv[k].y; }

    float* orow = out + ((size_t)BB + (size_t)j * NEXP) * DD;
    #pragma unroll
    for (int r = 0; r < 16; ++r) {
        float o0 = 0.0f, o1 = 0.0f;
        #pragma unroll
        for (int jj = 0; jj < 18; ++jj) {
            float cc = G[r][jj];                  // broadcast read
            o0 += cc * Br0[jj];
            o1 += cc * Br1[jj];
        }
        float2 ov = { M.x + r1n * o0, M.y + r1n * o1 };
        ((float2*)(orow + (size_t)r * DD))[t] = ov;
    }

    if (t < NEXP) out[AUGT_OFF + BB + (size_t)j * NEXP + t] = (float)cls;
}

// ---------------------------------------------------------------------------
extern "C" void kernel_launch(void* const* d_in, const int* in_sizes, int n_in,
                              void* d_out, int out_size, void* d_ws, size_t ws_size,
                              hipStream_t stream)
{
    const float* x     = (const float*)d_in[0];   // [8192,512]
    const int*   y     = (const int*)d_in[1];     // [8192]
    const float* prox  = (const float*)d_in[2];   // [11318,512]
    const float* bw    = (const float*)d_in[3];   // [17,17]
    const float* rands = (const float*)d_in[4];   // [2048,16,512]
    float* out = (float*)d_out;

    double* scores = (double*)d_ws;                           // 64 KB
    int* ranks = (int*)((char*)d_ws + 65536);                 // 32 KB
    int* sel   = (int*)((char*)d_ws + 65536 + 32768);         // 8 KB

    hipMemsetAsync(ranks, 0, BB * sizeof(int), stream);

    score_kernel<<<BB, 64, 0, stream>>>(x, y, prox, scores);
    dim3 rgrid(BB / 256, BB / JCHUNK);
    rank_kernel<<<rgrid, 256, 0, stream>>>(scores, ranks);
    compact_kernel<<<1, 256, 0, stream>>>(ranks, sel, out);
    copy_kernel<<<1024, 256, 0, stream>>>(x, y, out);
    expand_kernel<<<TOPK, 256, 0, stream>>>(x, y, prox, bw, rands, sel, out);
}